// Round 1
// 3157.389 us; speedup vs baseline: 1.0035x; 1.0035x over previous
//
#include <hip/hip_runtime.h>

#define L_SEQ 2048
#define DE 768
#define DV 64
#define NH 12
#define DMLP 3072
#define NVOCAB 32000
#define NLAYERS 4

typedef float f32x4 __attribute__((ext_vector_type(4)));
typedef __bf16 bf16x8 __attribute__((ext_vector_type(8)));

__device__ __forceinline__ unsigned short f2bf(float f) {
  union { float f; unsigned int u; } x; x.f = f;
  unsigned int r = x.u + 0x7fffu + ((x.u >> 16) & 1u);
  return (unsigned short)(r >> 16);
}
__device__ __forceinline__ float bf2f(unsigned short u) {
  union { unsigned int u; float f; } x; x.u = ((unsigned int)u) << 16;
  return x.f;
}
__device__ __forceinline__ float gelu_f(float x) {
  float x3 = x * x * x;
  return 0.5f * x * (1.f + tanhf(0.7978845608028654f * (x + 0.044715f * x3)));
}

// async global->LDS, 16B per lane. LDS dest must be the wave-uniform base;
// HW scatters lane i at base + i*16 (m104). Source address is per-lane.
__device__ __forceinline__ void gld_lds16(const void* g, void* lds) {
  __builtin_amdgcn_global_load_lds(
      (__attribute__((address_space(1))) void*)g,
      (__attribute__((address_space(3))) void*)lds, 16, 0, 0);
}

// ---------------- embed: Y[l,:] = word_embed[x[l],:] + pos_embed[l,:] ----------------
__global__ void embed_kernel(const int* __restrict__ x, const float* __restrict__ we,
                             const float* __restrict__ pe, float* __restrict__ Y) {
  int l = blockIdx.x;
  int id = x[l];
  for (int c = threadIdx.x; c < DE; c += 256)
    Y[(long)l * DE + c] = we[(long)id * DE + c] + pe[(long)l * DE + c];
}

// ---------------- layernorm (population std, std==0 -> 1) ----------------
__global__ void layernorm_kernel(const float* __restrict__ X, const float* __restrict__ g,
                                 const float* __restrict__ be, float* __restrict__ outf,
                                 unsigned short* __restrict__ outb) {
  __shared__ float red1[4], red2[4];
  int row = blockIdx.x;
  const float* xr = X + (long)row * DE;
  int tid = threadIdx.x;
  float xv[3];
  float s = 0.f, sq = 0.f;
#pragma unroll
  for (int j = 0; j < 3; j++) {
    float v = xr[tid + 256 * j];
    xv[j] = v; s += v; sq += v * v;
  }
#pragma unroll
  for (int o = 32; o; o >>= 1) { s += __shfl_down(s, o, 64); sq += __shfl_down(sq, o, 64); }
  int wave = tid >> 6, lane = tid & 63;
  if (lane == 0) { red1[wave] = s; red2[wave] = sq; }
  __syncthreads();
  s = red1[0] + red1[1] + red1[2] + red1[3];
  sq = red2[0] + red2[1] + red2[2] + red2[3];
  float mean = s * (1.f / DE);
  float var = fmaxf(sq * (1.f / DE) - mean * mean, 0.f);
  float sd = sqrtf(var);
  if (sd == 0.f) sd = 1.f;
  float inv = 1.f / sd;
#pragma unroll
  for (int j = 0; j < 3; j++) {
    int c = tid + 256 * j;
    float o = g[c] * ((xv[j] - mean) * inv) + be[c];
    if (outf) outf[(long)row * DE + c] = o;
    outb[(long)row * DE + c] = f2bf(o);
  }
}

// ---------------- transpose + f32->bf16: in (R x C) -> out (C x R) ----------------
__global__ void transpose_cvt(const float* __restrict__ in, long sInZ,
                              unsigned short* __restrict__ out, long sOutZ, int R, int C) {
  __shared__ float tile[32][33];
  const float* inz = in + (long)blockIdx.z * sInZ;
  unsigned short* outz = out + (long)blockIdx.z * sOutZ;
  int c0 = blockIdx.x * 32, r0 = blockIdx.y * 32;
  int tx = threadIdx.x, ty = threadIdx.y;
#pragma unroll
  for (int j = 0; j < 32; j += 8) {
    int r = r0 + ty + j, c = c0 + tx;
    tile[ty + j][tx] = (r < R && c < C) ? inz[(long)r * C + c] : 0.f;
  }
  __syncthreads();
#pragma unroll
  for (int j = 0; j < 32; j += 8) {
    int orow = c0 + ty + j, oc = r0 + tx;
    if (orow < C && oc < R) outz[(long)orow * R + oc] = f2bf(tile[tx][ty + j]);
  }
}

// ---------------- transpose bf16: in (R x C) -> out (C x R) ----------------
__global__ void transpose_bf16(const unsigned short* __restrict__ in, long sInZ,
                               unsigned short* __restrict__ out, long sOutZ, int R, int C) {
  __shared__ unsigned short tile[32][33];
  const unsigned short* inz = in + (long)blockIdx.z * sInZ;
  unsigned short* outz = out + (long)blockIdx.z * sOutZ;
  int c0 = blockIdx.x * 32, r0 = blockIdx.y * 32;
  int tx = threadIdx.x, ty = threadIdx.y;
#pragma unroll
  for (int j = 0; j < 32; j += 8) {
    int r = r0 + ty + j, c = c0 + tx;
    tile[ty + j][tx] = (r < R && c < C) ? inz[(long)r * C + c] : (unsigned short)0;
  }
  __syncthreads();
#pragma unroll
  for (int j = 0; j < 32; j += 8) {
    int orow = c0 + ty + j, oc = r0 + tx;
    if (orow < C && oc < R) outz[(long)orow * R + oc] = tile[tx][ty + j];
  }
}

// ---------------- row softmax, bf16 in-place, cols = 2048, 16B/lane ----------------
__global__ void softmax_rows_bf16(unsigned short* __restrict__ S) {
  __shared__ float redm[4], reds[4];
  long row = blockIdx.x;
  unsigned short* s = S + row * (long)L_SEQ;
  int tid = threadIdx.x;
  union { uint4 u; unsigned short us[8]; } pk;
  pk.u = *(const uint4*)(s + tid * 8);
  float v[8];
  float m = -1e30f;
#pragma unroll
  for (int j = 0; j < 8; j++) { v[j] = bf2f(pk.us[j]); m = fmaxf(m, v[j]); }
#pragma unroll
  for (int o = 1; o < 64; o <<= 1) m = fmaxf(m, __shfl_xor(m, o, 64));
  int wave = tid >> 6, lane = tid & 63;
  if (lane == 0) redm[wave] = m;
  __syncthreads();
  m = fmaxf(fmaxf(redm[0], redm[1]), fmaxf(redm[2], redm[3]));
  float sum = 0.f;
#pragma unroll
  for (int j = 0; j < 8; j++) { v[j] = __expf(v[j] - m); sum += v[j]; }
#pragma unroll
  for (int o = 1; o < 64; o <<= 1) sum += __shfl_xor(sum, o, 64);
  if (lane == 0) reds[wave] = sum;
  __syncthreads();
  sum = reds[0] + reds[1] + reds[2] + reds[3];
  float inv = 1.f / sum;
#pragma unroll
  for (int j = 0; j < 8; j++) pk.us[j] = f2bf(v[j] * inv);
  *(uint4*)(s + tid * 8) = pk.u;
}

// ---------------- row softmax, f32 in-place, cols % 4 == 0, float4 loads ----------------
__global__ void softmax_rows_f32(float* __restrict__ S, int cols) {
  __shared__ float redm[4], reds[4];
  long row = blockIdx.x;
  f32x4* s4 = (f32x4*)(S + row * (long)cols);
  const int n4 = cols >> 2;
  int tid = threadIdx.x;
  float m = -1e30f, sum = 0.f;
  for (int c = tid; c < n4; c += 256) {
    f32x4 v = s4[c];
    float mc = fmaxf(fmaxf(v[0], v[1]), fmaxf(v[2], v[3]));
    if (mc > m) { sum *= __expf(m - mc); m = mc; }
    sum += __expf(v[0] - m) + __expf(v[1] - m) + __expf(v[2] - m) + __expf(v[3] - m);
  }
#pragma unroll
  for (int o = 1; o < 64; o <<= 1) {
    float m2 = __shfl_xor(m, o, 64), s2 = __shfl_xor(sum, o, 64);
    float M = fmaxf(m, m2);
    sum = sum * __expf(m - M) + s2 * __expf(m2 - M);
    m = M;
  }
  int wave = tid >> 6, lane = tid & 63;
  if (lane == 0) { redm[wave] = m; reds[wave] = sum; }
  __syncthreads();
  float M = fmaxf(fmaxf(redm[0], redm[1]), fmaxf(redm[2], redm[3]));
  float ssum = reds[0] * __expf(redm[0] - M) + reds[1] * __expf(redm[1] - M) +
               reds[2] * __expf(redm[2] - M) + reds[3] * __expf(redm[3] - M);
  float inv = 1.f / ssum;
  for (int c = tid; c < n4; c += 256) {
    f32x4 v = s4[c];
    v[0] = __expf(v[0] - M) * inv;
    v[1] = __expf(v[1] - M) * inv;
    v[2] = __expf(v[2] - M) * inv;
    v[3] = __expf(v[3] - M) * inv;
    s4[c] = v;
  }
}

// ---------------- assemble y from attn (faithful overlapping-head-writes semantics) ----------------
__global__ void assemble_y(const unsigned short* __restrict__ attn, unsigned short* __restrict__ y) {
  int l = blockIdx.x;
  for (int c = threadIdx.x; c < DE; c += 256) {
    unsigned short v = 0;
    if (c < NH - 1) v = attn[(long)c * L_SEQ * DV + (long)l * DV + 0];
    else if (c < NH - 1 + DV) v = attn[(long)(NH - 1) * L_SEQ * DV + (long)l * DV + (c - (NH - 1))];
    y[(long)l * DE + c] = v;
  }
}

// ---------------- bf16 MFMA GEMM: C = act(scale*(A @ B^T) + bias) + alpha*res1 + res2 ----------------
// A: M x K bf16 row-major.  B: N x K bf16 row-major (B^T of the math op).
// 128x128 block tile, BK=32, 4 waves each computing 64x64 via 4x4 MFMA 16x16x32.
// Staging is global_load_lds (direct-to-LDS DMA, 16B/lane): LDS layout is linear in tid
// (byte offset tid*16) = wave-uniform base + lane*16, exactly the HW pattern (m97/m151).
// OOB B rows are clamped to row N-1: duplicated data only feeds output cols >= N,
// which the epilogue skips.
template <bool OUT_BF16, bool GELU_ACT>
__global__ __launch_bounds__(256) void gemm_bf16(
    const unsigned short* __restrict__ A, long sAz,
    const unsigned short* __restrict__ B, long sBz,
    void* __restrict__ Cv, long sCz,
    const float* __restrict__ bias, long sBiasz,
    const float* __restrict__ res1, float alpha,
    const float* __restrict__ res2,
    float scale, int M, int N, int K) {
  __shared__ unsigned short As[128 * 32];
  __shared__ unsigned short Bs[128 * 32];
  const int tid = threadIdx.x;
  const int z = blockIdx.z;
  const unsigned short* Az = A + (long)z * sAz;
  const unsigned short* Bz = B + (long)z * sBz;
  const float* biasz = bias ? (bias + (long)z * sBiasz) : nullptr;
  const int n0 = blockIdx.x * 128;
  const int m0 = blockIdx.y * 128;
  const int wave = tid >> 6;
  const int lane = tid & 63;
  const int wm = (wave >> 1) * 64;
  const int wn = (wave & 1) * 64;
  const int l16 = lane & 15;
  const int quad = lane >> 4;
  // staging: each thread covers 2 chunks of A and 2 of B (full 128x32 tile)
  const int r1 = tid >> 2;         // 0..63
  const int c1 = (tid & 3) * 8;    // 0,8,16,24
  const int wbase = wave * 512;    // wave-uniform LDS element base (64 lanes * 8 elems)

  f32x4 zero4 = {0.f, 0.f, 0.f, 0.f};
  f32x4 acc[4][4];
#pragma unroll
  for (int i = 0; i < 4; i++)
#pragma unroll
    for (int j = 0; j < 4; j++) acc[i][j] = zero4;

  const unsigned short* Ap0 = Az + (long)(m0 + r1) * K + c1;
  const unsigned short* Ap1 = Az + (long)(m0 + r1 + 64) * K + c1;
  const int brow0 = n0 + r1, brow1 = n0 + r1 + 64;
  const int brow0c = brow0 < N ? brow0 : N - 1;
  const int brow1c = brow1 < N ? brow1 : N - 1;
  const unsigned short* Bp0 = Bz + (long)brow0c * K + c1;
  const unsigned short* Bp1 = Bz + (long)brow1c * K + c1;

  for (int kk = 0; kk < K; kk += 32) {
    __syncthreads();                     // all waves done reading previous tile
    gld_lds16(Ap0 + kk, As + wbase);
    gld_lds16(Ap1 + kk, As + 2048 + wbase);
    gld_lds16(Bp0 + kk, Bs + wbase);
    gld_lds16(Bp1 + kk, Bs + 2048 + wbase);
    __syncthreads();                     // compiler drains vmcnt(0) before barrier
    bf16x8 af[4], bfv[4];
#pragma unroll
    for (int t = 0; t < 4; t++) {
      af[t]  = *(const bf16x8*)(&As[(wm + t * 16 + l16) * 32 + quad * 8]);
      bfv[t] = *(const bf16x8*)(&Bs[(wn + t * 16 + l16) * 32 + quad * 8]);
    }
#pragma unroll
    for (int mt = 0; mt < 4; mt++)
#pragma unroll
      for (int nt = 0; nt < 4; nt++)
        acc[mt][nt] = __builtin_amdgcn_mfma_f32_16x16x32_bf16(af[mt], bfv[nt], acc[mt][nt], 0, 0, 0);
  }

  // epilogue: C/D layout col = lane&15, row = quad*4 + r (m89-verified)
#pragma unroll
  for (int nt = 0; nt < 4; nt++) {
    const int col = n0 + wn + nt * 16 + l16;
    if (col >= N) continue;
    const float bval = biasz ? biasz[col] : 0.f;
#pragma unroll
    for (int mt = 0; mt < 4; mt++) {
#pragma unroll
      for (int r = 0; r < 4; r++) {
        const int row = m0 + wm + mt * 16 + quad * 4 + r;
        float v = acc[mt][nt][r] * scale + bval;
        if (GELU_ACT) v = gelu_f(v);
        const long idx = (long)row * N + col;
        if (res1) v += alpha * res1[idx];
        if (res2) v += res2[idx];
        if (OUT_BF16) ((unsigned short*)Cv)[(long)z * sCz + idx] = f2bf(v);
        else ((float*)Cv)[(long)z * sCz + idx] = v;
      }
    }
  }
}

extern "C" void kernel_launch(void* const* d_in, const int* in_sizes, int n_in,
                              void* d_out, int out_size, void* d_ws, size_t ws_size,
                              hipStream_t stream) {
  const int* x        = (const int*)d_in[0];
  const float* we     = (const float*)d_in[1];
  const float* pe     = (const float*)d_in[2];
  const float* Wq     = (const float*)d_in[3];
  const float* bq     = (const float*)d_in[4];
  const float* Wk     = (const float*)d_in[5];
  const float* bk     = (const float*)d_in[6];
  const float* Wv     = (const float*)d_in[7];
  const float* bv     = (const float*)d_in[8];
  const float* Wo     = (const float*)d_in[9];
  const float* bo     = (const float*)d_in[10];
  const float* g1     = (const float*)d_in[11];
  const float* be1    = (const float*)d_in[12];
  const float* g2     = (const float*)d_in[13];
  const float* be2    = (const float*)d_in[14];
  const float* W1     = (const float*)d_in[15];
  const float* bm1    = (const float*)d_in[16];
  const float* W2     = (const float*)d_in[17];
  const float* bm2    = (const float*)d_in[18];
  const float* gf     = (const float*)d_in[19];
  const float* bef    = (const float*)d_in[20];
  const float* Wu     = (const float*)d_in[21];
  const float* bu     = (const float*)d_in[22];
  float* out          = (float*)d_out;
  const int L = L_SEQ;

  char* base = (char*)d_ws;
  size_t off = 0;
  auto alloc = [&](size_t b) -> void* {
    void* p = base + off;
    off = (off + b + 255) & ~(size_t)255;
    return p;
  };
  float* Yf             = (float*)alloc((size_t)L * DE * 4);
  float* normf          = (float*)alloc((size_t)L * DE * 4);       // zn (f32)
  unsigned short* normb = (unsigned short*)alloc((size_t)L * DE * 2);
  unsigned short* Qb    = (unsigned short*)alloc((size_t)NH * L * DE * 2);
  unsigned short* Kb    = (unsigned short*)alloc((size_t)NH * L * DE * 2);
  unsigned short* Vb    = (unsigned short*)alloc((size_t)NH * L * DV * 2);
  unsigned short* Vtb   = (unsigned short*)alloc((size_t)NH * DV * L * 2);
  unsigned short* attnb = (unsigned short*)alloc((size_t)NH * L * DV * 2);
  unsigned short* yb    = (unsigned short*)alloc((size_t)L * DE * 2);
  unsigned short* hb    = (unsigned short*)alloc((size_t)L * DMLP * 2);
  unsigned short* wqt   = (unsigned short*)alloc((size_t)NH * DE * DE * 2);
  unsigned short* wkt   = (unsigned short*)alloc((size_t)NH * DE * DE * 2);
  unsigned short* wvt   = (unsigned short*)alloc((size_t)NH * DV * DE * 2);
  unsigned short* wot   = (unsigned short*)alloc((size_t)DE * DE * 2);
  unsigned short* w1t   = (unsigned short*)alloc((size_t)DMLP * DE * 2);
  unsigned short* w2t   = (unsigned short*)alloc((size_t)DE * DMLP * 2);
  unsigned short* scores= (unsigned short*)alloc((size_t)NH * L * L * 2);
  unsigned short* wut   = scores;  // overlap: Wu^T only needed after last attention
  (void)ws_size; (void)in_sizes; (void)n_in; (void)out_size;

  const dim3 tb(256);
  const dim3 tt(32, 8);
  const float inv_sqrt_de = 0.03608439182435161f;  // 1/sqrt(768)

  // embedding
  embed_kernel<<<dim3(L), tb, 0, stream>>>(x, we, pe, Yf);

  for (int i = 0; i < NLAYERS; i++) {
    // per-layer weight transposes (f32 -> bf16, N x K layout)
    transpose_cvt<<<dim3(24, 24, NH), tt, 0, stream>>>(Wq + (long)i * NH * DE * DE, (long)DE * DE, wqt, (long)DE * DE, DE, DE);
    transpose_cvt<<<dim3(24, 24, NH), tt, 0, stream>>>(Wk + (long)i * NH * DE * DE, (long)DE * DE, wkt, (long)DE * DE, DE, DE);
    transpose_cvt<<<dim3(2, 24, NH), tt, 0, stream>>>(Wv + (long)i * NH * DE * DV, (long)DE * DV, wvt, (long)DV * DE, DE, DV);
    transpose_cvt<<<dim3(24, 24, 1), tt, 0, stream>>>(Wo + (long)i * DE * DE, 0, wot, 0, DE, DE);
    transpose_cvt<<<dim3(96, 24, 1), tt, 0, stream>>>(W1 + (long)i * DE * DMLP, 0, w1t, 0, DE, DMLP);
    transpose_cvt<<<dim3(24, 96, 1), tt, 0, stream>>>(W2 + (long)i * DMLP * DE, 0, w2t, 0, DMLP, DE);

    // xn = LN(Y, g1, be1) -> bf16 only
    layernorm_kernel<<<dim3(L), tb, 0, stream>>>(Yf, g1 + (long)i * DE, be1 + (long)i * DE, nullptr, normb);

    // Q, K: (L x 768) per head, bf16 out with bias
    gemm_bf16<true, false><<<dim3(6, 16, NH), tb, 0, stream>>>(
        normb, 0L, wqt, (long)DE * DE, Qb, (long)L * DE,
        bq + (long)i * NH * DE, (long)DE, nullptr, 0.f, nullptr, 1.f, L, DE, DE);
    gemm_bf16<true, false><<<dim3(6, 16, NH), tb, 0, stream>>>(
        normb, 0L, wkt, (long)DE * DE, Kb, (long)L * DE,
        bk + (long)i * NH * DE, (long)DE, nullptr, 0.f, nullptr, 1.f, L, DE, DE);
    // V: (L x 64) per head
    gemm_bf16<true, false><<<dim3(1, 16, NH), tb, 0, stream>>>(
        normb, 0L, wvt, (long)DV * DE, Vb, (long)L * DV,
        bv + (long)i * NH * DV, (long)DV, nullptr, 0.f, nullptr, 1.f, L, DV, DE);

    // scores = Q @ K^T / sqrt(768)  (bf16)
    gemm_bf16<true, false><<<dim3(16, 16, NH), tb, 0, stream>>>(
        Qb, (long)L * DE, Kb, (long)L * DE, scores, (long)L * L,
        nullptr, 0L, nullptr, 0.f, nullptr, inv_sqrt_de, L, L, DE);

    // softmax over last dim, in place
    softmax_rows_bf16<<<dim3(NH * L), tb, 0, stream>>>(scores);

    // V^T for the P@V GEMM
    transpose_bf16<<<dim3(2, 64, NH), tt, 0, stream>>>(Vb, (long)L * DV, Vtb, (long)DV * L, L, DV);

    // attn = P @ V  (L x 64 per head, bf16)
    gemm_bf16<true, false><<<dim3(1, 16, NH), tb, 0, stream>>>(
        scores, (long)L * L, Vtb, (long)DV * L, attnb, (long)L * DV,
        nullptr, 0L, nullptr, 0.f, nullptr, 1.f, L, DV, L);

    // faithful overlapping-head-write concat
    assemble_y<<<dim3(L), tb, 0, stream>>>(attnb, yb);

    // Y = 2*Y + y @ Wo + bo   (f32, in place on Y)
    gemm_bf16<false, false><<<dim3(6, 16, 1), tb, 0, stream>>>(
        yb, 0L, wot, 0L, Yf, 0L,
        bo + (long)i * DE, 0L, Yf, 2.f, nullptr, 1.f, L, DE, DE);

    // zn = LN(Y, g2, be2) -> f32 + bf16
    layernorm_kernel<<<dim3(L), tb, 0, stream>>>(Yf, g2 + (long)i * DE, be2 + (long)i * DE, normf, normb);

    // h = gelu(zn @ W1 + bm1)  (bf16)
    gemm_bf16<true, true><<<dim3(24, 16, 1), tb, 0, stream>>>(
        normb, 0L, w1t, 0L, hb, 0L,
        bm1 + (long)i * DMLP, 0L, nullptr, 0.f, nullptr, 1.f, L, DMLP, DE);

    // Y = Y + zn + h @ W2 + bm2  (f32, in place on Y)
    gemm_bf16<false, false><<<dim3(6, 16, 1), tb, 0, stream>>>(
        hb, 0L, w2t, 0L, Yf, 0L,
        bm2 + (long)i * DE, 0L, Yf, 1.f, normf, 1.f, L, DE, DMLP);
  }

  // final LN
  layernorm_kernel<<<dim3(L), tb, 0, stream>>>(Yf, gf, bef, nullptr, normb);

  // Wu^T (32000 x 768 bf16) into the (now free) scores buffer
  transpose_cvt<<<dim3(1000, 24, 1), tt, 0, stream>>>(Wu, 0, wut, 0, DE, NVOCAB);

  // logits = Yn @ Wu + bu  -> d_out (f32)
  gemm_bf16<false, false><<<dim3(250, 16, 1), tb, 0, stream>>>(
      normb, 0L, wut, 0L, out, 0L,
      bu, 0L, nullptr, 0.f, nullptr, 1.f, L, NVOCAB, DE);

  // softmax rows (32000), in place on d_out
  softmax_rows_f32<<<dim3(L), tb, 0, stream>>>(out, NVOCAB);
}